// Round 8
// baseline (288.398 us; speedup 1.0000x reference)
//
#include <hip/hip_runtime.h>
#include <hip/hip_bf16.h>
#include <stdint.h>
#include <stddef.h>

typedef __attribute__((ext_vector_type(8))) short short8;
typedef __attribute__((ext_vector_type(4))) float f32x4;
typedef __attribute__((ext_vector_type(16))) float f32x16;

#define MFMA16(a, b, c) __builtin_amdgcn_mfma_f32_16x16x32_bf16((a), (b), (c), 0, 0, 0)
#define MFMA32(a, b, c) __builtin_amdgcn_mfma_f32_32x32x16_bf16((a), (b), (c), 0, 0, 0)

// Q pre-scale: HEAD_DIM^-0.5 * log2(e); flash uses raw v_exp_f32 (exp2)
#define QSCALE 0.1803368801111204f

#if __has_builtin(__builtin_amdgcn_exp2f)
#define EXP2(x) __builtin_amdgcn_exp2f(x)
#else
#define EXP2(x) __builtin_exp2f(x)
#endif

__device__ __forceinline__ float b2f(short x) {
    unsigned u = ((unsigned)(unsigned short)x) << 16;
    float f; __builtin_memcpy(&f, &u, 4); return f;
}
// round-nearest-even f32->bf16 (scalar)
__device__ __forceinline__ short f2b(float f) {
    unsigned u; __builtin_memcpy(&u, &f, 4);
    u = (u + 0x7FFFu + ((u >> 16) & 1u)) >> 16;
    return (short)u;
}
// two f32 -> packed bf16x2 in 3 VALU (2 adds + v_perm), round-half-up.
__device__ __forceinline__ unsigned pack2(float a, float b) {
    unsigned ua, ub; __builtin_memcpy(&ua, &a, 4); __builtin_memcpy(&ub, &b, 4);
    return __builtin_amdgcn_perm(ub + 0x8000u, ua + 0x8000u, 0x07060302u);
}
// two f32 -> packed bf16x2 in ONE VALU (RNE, same as f2b). low=a, high=b.
__device__ __forceinline__ unsigned cvtpk(float a, float b) {
    unsigned r;
    asm("v_cvt_pk_bf16_f32 %0, %1, %2" : "=v"(r) : "v"(a), "v"(b));
    return r;
}
// 8 contiguous f32 -> bf16x8 (RNE) in 2 loads + 4 cvtpk
__device__ __forceinline__ short8 cvt8f(const float* p) {
    const float4 f0 = *(const float4*)p;
    const float4 f1 = *(const float4*)(p + 4);
    uint4 u = { cvtpk(f0.x, f0.y), cvtpk(f0.z, f0.w),
                cvtpk(f1.x, f1.y), cvtpk(f1.z, f1.w) };
    return *(short8*)&u;
}
// combine two bf16x8 partials with f32 weights -> bf16x8 (RNE)
__device__ __forceinline__ short8 comb8(short8 a0, short8 a1, float w0, float w1) {
    float f[8];
#pragma unroll
    for (int e = 0; e < 8; e++) f[e] = w0 * b2f(a0[e]) + w1 * b2f(a1[e]);
    uint4 u = { cvtpk(f[0], f[1]), cvtpk(f[2], f[3]),
                cvtpk(f[4], f[5]), cvtpk(f[6], f[7]) };
    return *(short8*)&u;
}

// ---------------------------------------------------------------------------
// Fused QKV GEMM — r24: reads X and W as f32 DIRECTLY (cvt3 deleted),
// converting to bf16 fragments inline via v_cvt_pk_bf16_f32 (bit-identical
// RNE to the old f2b staging, 4 VALU per 8 elems). X re-reads (12x) hit L3.
// Grid (64,12): sec = y>>2 (0=Q,1=K,2=V).
//   Q (x QSCALE) -> Qb[bh][seq][64];  K -> Kb[bh][seq][64]
//   V -> Vb[bh][64][seq] via LDS-transposed epilogue (coalesced b128 stores)
// Q/K epilogue staged via LDS (r22): scalar ds_write, then 128-B row
// streams per thread.
// ---------------------------------------------------------------------------
__global__ __launch_bounds__(256) void qkv_gemm(
    const float* __restrict__ X, const float* __restrict__ W,
    const float* __restrict__ bias,
    short* __restrict__ Qb, short* __restrict__ Kb, short* __restrict__ Vb)
{
    __shared__ short sT[128][132];

    const int tid  = threadIdx.x;
    const int wv   = tid >> 6;
    const int lane = tid & 63;
    const int l15  = lane & 15;
    const int quad = lane >> 4;
    const int m0   = blockIdx.x * 128 + (wv >> 1) * 64;
    const int sec  = blockIdx.y >> 2;
    const int bis  = blockIdx.y & 3;
    const int nbase = sec * 512 + bis * 128;
    const int j0   = (wv & 1) * 64;

    const f32x4 zero = {0.f, 0.f, 0.f, 0.f};
    f32x4 acc[4][4];
#pragma unroll
    for (int i = 0; i < 4; i++)
#pragma unroll
        for (int j = 0; j < 4; j++) acc[i][j] = zero;

    const float* Arow = X + (size_t)(m0 + l15) * 512 + quad * 8;
    const float* Brow = W + (size_t)(nbase + j0 + l15) * 512 + quad * 8;

#pragma unroll 2
    for (int k0 = 0; k0 < 512; k0 += 32) {
        short8 a[4], b[4];
#pragma unroll
        for (int i = 0; i < 4; i++) a[i] = cvt8f(Arow + (size_t)i * 16 * 512 + k0);
#pragma unroll
        for (int j = 0; j < 4; j++) b[j] = cvt8f(Brow + (size_t)j * 16 * 512 + k0);
#pragma unroll
        for (int i = 0; i < 4; i++)
#pragma unroll
            for (int j = 0; j < 4; j++)
                acc[i][j] = MFMA16(a[i], b[j], acc[i][j]);
    }

    if (sec < 2) {
        const float scale = (sec == 0) ? QSCALE : 1.0f;
        short* dst = (sec == 0) ? Qb : Kb;
        // stage into sT[seqlocal][jcl]: 128 seq x 128 section-cols
#pragma unroll
        for (int j = 0; j < 4; j++) {
            const int jcl = j0 + j * 16 + l15;              // 0..127 block-local col
            const float bs = bias[sec * 512 + bis * 128 + jcl];
#pragma unroll
            for (int i = 0; i < 4; i++) {
                const int s0 = (wv >> 1) * 64 + i * 16 + quad * 4;  // seqlocal base
#pragma unroll
                for (int r = 0; r < 4; r++)
                    sT[s0 + r][jcl] = f2b((acc[i][j][r] + bs) * scale);
            }
        }
        __syncthreads();

        // write out: 256 rows (2 hl x 128 seq); thread owns one 128-B row
        const int seqlocal = tid & 127;
        const int hl_loc   = tid >> 7;                      // 0/1
        const int hl  = bis * 2 + hl_loc;
        const int m   = blockIdx.x * 128 + seqlocal;
        const int bb  = m >> 12, seqg = m & 4095;
        short* drow = dst + ((size_t)(bb * 8 + hl) * 4096 + seqg) * 64;
#pragma unroll
        for (int u = 0; u < 8; u++)
            *(short8*)(drow + u * 8) = *(const short8*)&sT[seqlocal][hl_loc * 64 + u * 8];
    } else {
        // V: pack 4 consecutive seq into b64 LDS writes, then coalesced b128
#pragma unroll
        for (int j = 0; j < 4; j++) {
            const int jcl = j0 + j * 16 + l15;             // 0..127
            const float bs = bias[nbase + jcl];
#pragma unroll
            for (int i = 0; i < 4; i++) {
                uint2 w;
                w.x = pack2(acc[i][j][0] + bs, acc[i][j][1] + bs);
                w.y = pack2(acc[i][j][2] + bs, acc[i][j][3] + bs);
                *(uint2*)&sT[jcl][(wv >> 1) * 64 + i * 16 + quad * 4] = w;
            }
        }
        __syncthreads();

        const int jcl = tid >> 1, half = tid & 1;
        const int hl = (bis * 128 + jcl) >> 6;
        const int d  = jcl & 63;
        const int bb = (blockIdx.x * 128) >> 12;
        const int seq0 = ((blockIdx.x * 128) & 4095) + half * 64;
        short* dst = Vb + ((size_t)(bb * 8 + hl) * 64 + d) * 4096 + seq0;
#pragma unroll
        for (int u = 0; u < 8; u++)
            *(short8*)(dst + u * 8) = *(const short8*)&sT[jcl][half * 64 + u * 8];
    }
}

// ---------------------------------------------------------------------------
// Flash attention — byte-identical to r7's proven 76.5us kernel: dbuf, ONE
// barrier/tile, register-P via bit2<->3-swapped V LDS, o2 row-sum on the
// MFMA pipe, wave stagger, cvtpk. Latency-bound at 4 waves/SIMD.
// Split-K=2 partials (no-max streaming softmax): O = (l0*O0+l1*O1)/(l0+l1).
// ---------------------------------------------------------------------------
__global__ __launch_bounds__(512, 4) void flash_attn(
    const short* __restrict__ Q, const short* __restrict__ K,
    const short* __restrict__ V, short* __restrict__ PO0,
    short* __restrict__ PO1, float* __restrict__ lbuf, int niter)
{
    __shared__ short sK[2][128][72];     // [buf][key][d], +8 pad
    __shared__ short sV[2][64][136];     // [buf][d][key-bitswapped], +8 pad

    const int tid  = threadIdx.x;
    const int wv   = tid >> 6;            // 0..7
    const int lane = tid & 63;
    const int l31  = lane & 31;
    const int half = lane >> 5;           // 0/1
    const int bh = blockIdx.y;
    const int b = bh >> 3, h = bh & 7;
    const int qw = blockIdx.x * 256 + wv * 32;   // wave's 32 queries
    const int ks = blockIdx.z;
    const int key0 = ks * niter * 128;

    const short* Qb = Q + (size_t)bh * 4096 * 64;
    const short* Kb = K + (size_t)bh * 4096 * 64;
    const short* Vb = V + (size_t)bh * 64 * 4096;

    // Q B-frags: B[k=d][n=query l31]; step s covers d = s*16 + half*8 + j
    short8 aq[4];
#pragma unroll
    for (int s = 0; s < 4; s++)
        aq[s] = *(const short8*)(Qb + (size_t)(qw + l31) * 64 + s * 16 + half * 8);

    // ones A-frag for the row-sum MFMA (bf16 1.0 = 0x3F80)
    short8 ones;
#pragma unroll
    for (int j = 0; j < 8; j++) ones[j] = (short)0x3F80;

    f32x16 o0 = {}, o1 = {};              // O^T acc, d-tiles 0/1 (col=query)
    f32x16 o2 = {};                       // row-sum acc (any reg = lsum)

    // staging: 512 threads x (2 K-chunks + 2 V-chunks) per 128-key tile
    const int r0  = tid >> 3;             // 0..63
    const int scb = (tid & 7) * 8;        // 0..56
    const int vb  = (scb & ~12) | ((scb & 8) >> 1);  // bit2<->bit3 swap base

    short8 pk0, pk1, pv0, pv1;
    // tile 0 -> buf 0 (no barrier needed yet: LDS untouched)
    pk0 = *(const short8*)(Kb + (size_t)(key0 + r0) * 64 + scb);
    pk1 = *(const short8*)(Kb + (size_t)(key0 + 64 + r0) * 64 + scb);
    pv0 = *(const short8*)(Vb + (size_t)r0 * 4096 + key0 + scb);
    pv1 = *(const short8*)(Vb + (size_t)r0 * 4096 + key0 + 64 + scb);
    *(short8*)&sK[0][r0][scb]      = pk0;
    *(short8*)&sK[0][64 + r0][scb] = pk1;
    *(uint2*)&sV[0][r0][vb]          = ((const uint2*)&pv0)[0];
    *(uint2*)&sV[0][r0][vb + 8]      = ((const uint2*)&pv0)[1];
    *(uint2*)&sV[0][r0][64 + vb]     = ((const uint2*)&pv1)[0];
    *(uint2*)&sV[0][r0][64 + vb + 8] = ((const uint2*)&pv1)[1];
    // prefetch tile 1 into regs
    {
        const int kn = key0 + 128;
        pk0 = *(const short8*)(Kb + (size_t)(kn + r0) * 64 + scb);
        pk1 = *(const short8*)(Kb + (size_t)(kn + 64 + r0) * 64 + scb);
        pv0 = *(const short8*)(Vb + (size_t)r0 * 4096 + kn + scb);
        pv1 = *(const short8*)(Vb + (size_t)r0 * 4096 + kn + 64 + scb);
    }

    for (int kt = 0; kt < niter; ++kt) {
        __syncthreads();   // buf[kt&1] writes visible; prev reads of buf[(kt+1)&1] done

        if (kt + 1 < niter) {          // write tile kt+1 to the other buffer
            short (*sKn)[72]  = sK[(kt + 1) & 1];
            short (*sVn)[136] = sV[(kt + 1) & 1];
            *(short8*)&sKn[r0][scb]      = pk0;
            *(short8*)&sKn[64 + r0][scb] = pk1;
            *(uint2*)&sVn[r0][vb]          = ((const uint2*)&pv0)[0];
            *(uint2*)&sVn[r0][vb + 8]      = ((const uint2*)&pv0)[1];
            *(uint2*)&sVn[r0][64 + vb]     = ((const uint2*)&pv1)[0];
            *(uint2*)&sVn[r0][64 + vb + 8] = ((const uint2*)&pv1)[1];
        }
        if (kt + 2 < niter) {          // issue global loads for tile kt+2
            const int kn = key0 + (kt + 2) * 128;
            pk0 = *(const short8*)(Kb + (size_t)(kn + r0) * 64 + scb);
            pk1 = *(const short8*)(Kb + (size_t)(kn + 64 + r0) * 64 + scb);
            pv0 = *(const short8*)(Vb + (size_t)r0 * 4096 + kn + scb);
            pv1 = *(const short8*)(Vb + (size_t)r0 * 4096 + kn + 64 + scb);
        }

        const short (*sKc)[72]  = sK[kt & 1];
        const short (*sVc)[136] = sV[kt & 1];

        // 4 c-subtiles of 32 keys, WAVE-ROTATED order: c = (i + wv) & 3.
        // S^T C/D: col=query l31, reg r holds key c*32 + (r&3)+8*(r>>2)+4*half
#pragma unroll
        for (int i = 0; i < 4; i++) {
            const int c = (i + wv) & 3;
            f32x16 ST = {};
            __builtin_amdgcn_s_setprio(1);
#pragma unroll
            for (int s = 0; s < 4; s++) {
                const short8 bk = *(const short8*)&sKc[c * 32 + l31][s * 16 + half * 8];
                ST = MFMA32(bk, aq[s], ST);
            }
            __builtin_amdgcn_s_setprio(0);
            float e[16];
#pragma unroll
            for (int r = 0; r < 16; r++) e[r] = EXP2(ST[r]);
            uint4 w0 = { cvtpk(e[0], e[1]),   cvtpk(e[2], e[3]),
                         cvtpk(e[4], e[5]),   cvtpk(e[6], e[7]) };
            uint4 w1 = { cvtpk(e[8], e[9]),   cvtpk(e[10], e[11]),
                         cvtpk(e[12], e[13]), cvtpk(e[14], e[15]) };
            const short8 bp0 = *(const short8*)&w0;   // PV B-frag, step t=2c
            const short8 bp1 = *(const short8*)&w1;   // step t=2c+1

            // O^T += V^T x P^T ; o2 += 1 x P^T (row sums on the MFMA pipe)
            __builtin_amdgcn_s_setprio(1);
            const short8 bv00 = *(const short8*)&sVc[l31][(2 * c) * 16 + half * 8];
            const short8 bv01 = *(const short8*)&sVc[32 + l31][(2 * c) * 16 + half * 8];
            o0 = MFMA32(bv00, bp0, o0);
            o1 = MFMA32(bv01, bp0, o1);
            o2 = MFMA32(ones, bp0, o2);
            const short8 bv10 = *(const short8*)&sVc[l31][(2 * c + 1) * 16 + half * 8];
            const short8 bv11 = *(const short8*)&sVc[32 + l31][(2 * c + 1) * 16 + half * 8];
            o0 = MFMA32(bv10, bp1, o0);
            o1 = MFMA32(bv11, bp1, o1);
            o2 = MFMA32(ones, bp1, o2);
            __builtin_amdgcn_s_setprio(0);
        }
    }

    // o2[0] = full row sum for query l31 (all keys, both halves, all tiles)
    const float lsum = o2[0];
    const float inv = 1.f / fmaxf(lsum, 1e-30f);

    short* PO = (ks == 0) ? PO0 : PO1;
    // O^T: reg-quad q = 4 consecutive d at 8q + 4*half (+32 for o1), query l31
#pragma unroll
    for (int q = 0; q < 4; q++) {
        uint2 w0, w1;
        w0.x = pack2(o0[4 * q + 0] * inv, o0[4 * q + 1] * inv);
        w0.y = pack2(o0[4 * q + 2] * inv, o0[4 * q + 3] * inv);
        w1.x = pack2(o1[4 * q + 0] * inv, o1[4 * q + 1] * inv);
        w1.y = pack2(o1[4 * q + 2] * inv, o1[4 * q + 3] * inv);
        const size_t rowoff = ((size_t)b * 4096 + qw + l31) * 512;
        const int col = h * 64 + q * 8 + half * 4;
        *(uint2*)(PO + rowoff + col) = w0;
        *(uint2*)(PO + rowoff + col + 32) = w1;
    }
    if (half == 0)
        lbuf[((size_t)ks * 16 + bh) * 4096 + qw + l31] = lsum;
}

// ---------------------------------------------------------------------------
// Projection r24 — FUSED COMBINE (combine kernel deleted). Reads the two
// split-K partials PO0/PO1 (bf16) + lbuf, forms the combined bf16 A-frag
// in registers: a = cvtpk(w0*b2f(a0) + w1*b2f(a1)), w = l/(l0+l1).
// Head index for a k-block is wave-uniform (h = k0>>6), so per-head the
// 4 per-row weight pairs are hoisted (8 scalar L2 loads / head).
// W read as f32 directly (pwb deleted). Swapped-operand MFMA16(b,a) ->
// lane holds 4 consecutive output cols -> contiguous float4 stores.
// Grid (128,4) = 512 blocks = 2/CU. VALU combine work rides the idle pipe.
// ---------------------------------------------------------------------------
__global__ __launch_bounds__(256) void proj_fused(
    const short* __restrict__ PO0, const short* __restrict__ PO1,
    const float* __restrict__ L, const float* __restrict__ W,
    const float* __restrict__ bias, float* __restrict__ dst)
{
    const int tid  = threadIdx.x;
    const int wv   = tid >> 6;
    const int lane = tid & 63;
    const int l15  = lane & 15;
    const int quad = lane >> 4;
    const int m0 = blockIdx.x * 64;                 // 0..8191 (128 tiles)
    const int n0 = blockIdx.y * 128 + wv * 32;      // 0..511
    const int bb = m0 >> 12;                        // batch (tile-uniform)

    const f32x4 zero = {0.f, 0.f, 0.f, 0.f};
    f32x4 acc[4][2];
#pragma unroll
    for (int i = 0; i < 4; i++)
#pragma unroll
        for (int j = 0; j < 2; j++) acc[i][j] = zero;

    const short* A0row = PO0 + (size_t)(m0 + l15) * 512 + quad * 8;
    const short* A1row = PO1 + (size_t)(m0 + l15) * 512 + quad * 8;
    const float* Brow  = W + (size_t)(n0 + l15) * 512 + quad * 8;

    for (int h = 0; h < 8; ++h) {
        // per-row combine weights for this head (k-cols h*64..h*64+63)
        float w0v[4], w1v[4];
#pragma unroll
        for (int i = 0; i < 4; i++) {
            const int q = (m0 + i * 16 + l15) & 4095;
            const size_t off = (size_t)(bb * 8 + h) * 4096 + q;
            const float l0 = L[off];
            const float l1 = L[65536 + off];
            const float inv = 1.f / (l0 + l1);
            w0v[i] = l0 * inv; w1v[i] = l1 * inv;
        }
#pragma unroll
        for (int kk = 0; kk < 2; ++kk) {
            const int k0 = h * 64 + kk * 32;
            short8 a[4], b[2];
#pragma unroll
            for (int i = 0; i < 4; i++) {
                const short8 a0 = *(const short8*)(A0row + (size_t)i * 16 * 512 + k0);
                const short8 a1 = *(const short8*)(A1row + (size_t)i * 16 * 512 + k0);
                a[i] = comb8(a0, a1, w0v[i], w1v[i]);
            }
#pragma unroll
            for (int j = 0; j < 2; j++) b[j] = cvt8f(Brow + (size_t)j * 16 * 512 + k0);
            // swapped operands: D^T layout — l15 = A-row m, quad*4+r = W-col n
#pragma unroll
            for (int i = 0; i < 4; i++)
#pragma unroll
                for (int j = 0; j < 2; j++)
                    acc[i][j] = MFMA16(b[j], a[i], acc[i][j]);
        }
    }

    // acc[i][j][r] = out[m0 + i*16 + l15][n0 + j*16 + quad*4 + r]
#pragma unroll
    for (int i = 0; i < 4; i++) {
        const int m = m0 + i * 16 + l15;
#pragma unroll
        for (int j = 0; j < 2; j++) {
            const int n = n0 + j * 16 + quad * 4;
            const float4 bs = *(const float4*)(bias + n);
            float4 o;
            o.x = acc[i][j][0] + bs.x;
            o.y = acc[i][j][1] + bs.y;
            o.z = acc[i][j][2] + bs.z;
            o.w = acc[i][j][3] + bs.w;
            *(float4*)(dst + (size_t)m * 512 + n) = o;
        }
    }
}

// ---------------------------------------------------------------------------
// Memory plan — 3 dispatches, all read/write sets disjoint per kernel:
//   qkv:   reads x/qkv_w/qkv_b (f32 inputs); writes Qf(ws), Kf/Vf(d_out)
//   flash: reads Qf(ws), Kf/Vf(d_out); writes PO0/PO1/lbuf (ws)
//   proj:  reads PO0/PO1/lbuf(ws), proj_w/proj_b (inputs);
//          writes d_out f32 [0,16M) (Kf/Vf dead after flash — no race)
// ws: [0,8M) Qf | [8,16M) PO0 | [16,24M) PO1 | [24,24.5M) lbuf  = 24.5 MB
// ---------------------------------------------------------------------------
extern "C" void kernel_launch(void* const* d_in, const int* in_sizes, int n_in,
                              void* d_out, int out_size, void* d_ws, size_t ws_size,
                              hipStream_t stream)
{
    const float* x      = (const float*)d_in[0];   // [2,4096,512] f32
    const float* qkv_w  = (const float*)d_in[1];   // [1536,512]   f32
    const float* qkv_b  = (const float*)d_in[2];   // [1536]       f32
    const float* proj_w = (const float*)d_in[3];   // [512,512]    f32
    const float* proj_b = (const float*)d_in[4];   // [512]        f32

    const size_t MB = 1024 * 1024;
    short* Kf  = (short*)d_out;                        // d_out [0,8M)
    short* Vf  = (short*)d_out + 4 * MB;               // d_out [8,16M), [bh][64][seq]
    float* out = (float*)d_out;                        // proj output [0,16M)

    short* Qf   = (short*)d_ws;                        // ws [0,8M)
    short* PO0  = (short*)((char*)d_ws + 8 * MB);      // ws [8,16M)
    short* PO1  = (short*)((char*)d_ws + 16 * MB);     // ws [16,24M)
    float* lbuf = (float*)((char*)d_ws + 24 * MB);     // ws [24,24.5M)

    qkv_gemm<<<dim3(64, 12), 256, 0, stream>>>(x, qkv_w, qkv_b, Qf, Kf, Vf);
    flash_attn<<<dim3(16, 16, 2), 512, 0, stream>>>(Qf, Kf, Vf, PO0, PO1, lbuf, 16);
    proj_fused<<<dim3(128, 4), 256, 0, stream>>>(PO0, PO1, lbuf, proj_w, proj_b, out);
}

// Round 9
// 245.186 us; speedup vs baseline: 1.1762x; 1.1762x over previous
//
#include <hip/hip_runtime.h>
#include <hip/hip_bf16.h>
#include <stdint.h>
#include <stddef.h>

typedef __attribute__((ext_vector_type(8))) short short8;
typedef __attribute__((ext_vector_type(4))) float f32x4;
typedef __attribute__((ext_vector_type(16))) float f32x16;

#define MFMA16(a, b, c) __builtin_amdgcn_mfma_f32_16x16x32_bf16((a), (b), (c), 0, 0, 0)
#define MFMA32(a, b, c) __builtin_amdgcn_mfma_f32_32x32x16_bf16((a), (b), (c), 0, 0, 0)

// Q pre-scale: HEAD_DIM^-0.5 * log2(e); flash uses raw v_exp_f32 (exp2)
#define QSCALE 0.1803368801111204f

#if __has_builtin(__builtin_amdgcn_exp2f)
#define EXP2(x) __builtin_amdgcn_exp2f(x)
#else
#define EXP2(x) __builtin_exp2f(x)
#endif

__device__ __forceinline__ float b2f(short x) {
    unsigned u = ((unsigned)(unsigned short)x) << 16;
    float f; __builtin_memcpy(&f, &u, 4); return f;
}
// round-nearest-even f32->bf16 (scalar)
__device__ __forceinline__ short f2b(float f) {
    unsigned u; __builtin_memcpy(&u, &f, 4);
    u = (u + 0x7FFFu + ((u >> 16) & 1u)) >> 16;
    return (short)u;
}
// two f32 -> packed bf16x2 in 3 VALU (2 adds + v_perm), round-half-up.
__device__ __forceinline__ unsigned pack2(float a, float b) {
    unsigned ua, ub; __builtin_memcpy(&ua, &a, 4); __builtin_memcpy(&ub, &b, 4);
    return __builtin_amdgcn_perm(ub + 0x8000u, ua + 0x8000u, 0x07060302u);
}
// two f32 -> packed bf16x2 in ONE VALU (RNE). low=a, high=b.
__device__ __forceinline__ unsigned cvtpk(float a, float b) {
    unsigned r;
    asm("v_cvt_pk_bf16_f32 %0, %1, %2" : "=v"(r) : "v"(a), "v"(b));
    return r;
}
// 8 contiguous f32 -> bf16x8 (RNE)
__device__ __forceinline__ short8 load8f(const float* p) {
    const float4 f0 = *(const float4*)p;
    const float4 f1 = *(const float4*)(p + 4);
    short8 r;
    r[0]=f2b(f0.x); r[1]=f2b(f0.y); r[2]=f2b(f0.z); r[3]=f2b(f0.w);
    r[4]=f2b(f1.x); r[5]=f2b(f1.y); r[6]=f2b(f1.z); r[7]=f2b(f1.w);
    return r;
}
// combine two bf16x8 partials with f32 weights -> bf16x8 (RNE)
__device__ __forceinline__ short8 comb8(short8 a0, short8 a1, float w0, float w1) {
    float f[8];
#pragma unroll
    for (int e = 0; e < 8; e++) f[e] = w0 * b2f(a0[e]) + w1 * b2f(a1[e]);
    uint4 u = { cvtpk(f[0], f[1]), cvtpk(f[2], f[3]),
                cvtpk(f[4], f[5]), cvtpk(f[6], f[7]) };
    return *(short8*)&u;
}

// ---------------------------------------------------------------------------
// Fused f32->bf16 converter for up to 3 arrays. nX = elems/8.
// (RESTORED: r24's inline-f32 GEMM reads were the 99.6us qkv regression —
// bf16 staging + short8 loads is the proven-fast path.)
// ---------------------------------------------------------------------------
__global__ __launch_bounds__(256) void cvt3(
    const float* __restrict__ s0, short* __restrict__ d0, int n0,
    const float* __restrict__ s1, short* __restrict__ d1, int n1,
    const float* __restrict__ s2, short* __restrict__ d2, int n2)
{
    int i = blockIdx.x * 256 + threadIdx.x;
    if (i < n0) { *(short8*)(d0 + (size_t)i * 8) = load8f(s0 + (size_t)i * 8); return; }
    i -= n0;
    if (i < n1) { *(short8*)(d1 + (size_t)i * 8) = load8f(s1 + (size_t)i * 8); return; }
    i -= n1;
    if (i < n2) { *(short8*)(d2 + (size_t)i * 8) = load8f(s2 + (size_t)i * 8); }
}

// ---------------------------------------------------------------------------
// Fused QKV GEMM (bf16 in/out) — r7's proven kernel. Grid (64,12).
//   Q (x QSCALE) -> Qb[bh][seq][64];  K -> Kb[bh][seq][64]
//   V -> Vb[bh][64][seq] via LDS-transposed epilogue.
// 2-deep register prefetch in the K-loop (branchless wrap, unroll 2).
// ---------------------------------------------------------------------------
__global__ __launch_bounds__(256) void qkv_gemm(
    const short* __restrict__ X, const short* __restrict__ W,
    const float* __restrict__ bias,
    short* __restrict__ Qb, short* __restrict__ Kb, short* __restrict__ Vb)
{
    __shared__ short sT[128][132];

    const int tid  = threadIdx.x;
    const int wv   = tid >> 6;
    const int lane = tid & 63;
    const int l15  = lane & 15;
    const int quad = lane >> 4;
    const int m0   = blockIdx.x * 128 + (wv >> 1) * 64;
    const int sec  = blockIdx.y >> 2;
    const int bis  = blockIdx.y & 3;
    const int nbase = sec * 512 + bis * 128;
    const int j0   = (wv & 1) * 64;

    const f32x4 zero = {0.f, 0.f, 0.f, 0.f};
    f32x4 acc[4][4];
#pragma unroll
    for (int i = 0; i < 4; i++)
#pragma unroll
        for (int j = 0; j < 4; j++) acc[i][j] = zero;

    const short* Arow = X + (size_t)(m0 + l15) * 512 + quad * 8;
    const short* Brow = W + (size_t)(nbase + j0 + l15) * 512 + quad * 8;

    short8 a[4], b[4];
#pragma unroll
    for (int i = 0; i < 4; i++) a[i] = *(const short8*)(Arow + (size_t)i * 16 * 512);
#pragma unroll
    for (int j = 0; j < 4; j++) b[j] = *(const short8*)(Brow + (size_t)j * 16 * 512);

#pragma unroll 2
    for (int k0 = 0; k0 < 512; k0 += 32) {
        const int kn = (k0 + 32 < 512) ? k0 + 32 : 0;   // branchless wrap
        short8 an[4], bn[4];
#pragma unroll
        for (int i = 0; i < 4; i++) an[i] = *(const short8*)(Arow + (size_t)i * 16 * 512 + kn);
#pragma unroll
        for (int j = 0; j < 4; j++) bn[j] = *(const short8*)(Brow + (size_t)j * 16 * 512 + kn);
#pragma unroll
        for (int i = 0; i < 4; i++)
#pragma unroll
            for (int j = 0; j < 4; j++)
                acc[i][j] = MFMA16(a[i], b[j], acc[i][j]);
#pragma unroll
        for (int i = 0; i < 4; i++) a[i] = an[i];
#pragma unroll
        for (int j = 0; j < 4; j++) b[j] = bn[j];
    }

    if (sec < 2) {
        const float scale = (sec == 0) ? QSCALE : 1.0f;
        short* dst = (sec == 0) ? Qb : Kb;
        // stage into sT[seqlocal][jcl]: 128 seq x 128 section-cols
#pragma unroll
        for (int j = 0; j < 4; j++) {
            const int jcl = j0 + j * 16 + l15;              // 0..127 block-local col
            const float bs = bias[sec * 512 + bis * 128 + jcl];
#pragma unroll
            for (int i = 0; i < 4; i++) {
                const int s0 = (wv >> 1) * 64 + i * 16 + quad * 4;  // seqlocal base
#pragma unroll
                for (int r = 0; r < 4; r++)
                    sT[s0 + r][jcl] = f2b((acc[i][j][r] + bs) * scale);
            }
        }
        __syncthreads();

        // write out: 256 rows (2 hl x 128 seq); thread owns one 128-B row
        const int seqlocal = tid & 127;
        const int hl_loc   = tid >> 7;                      // 0/1
        const int hl  = bis * 2 + hl_loc;
        const int m   = blockIdx.x * 128 + seqlocal;
        const int bb  = m >> 12, seqg = m & 4095;
        short* drow = dst + ((size_t)(bb * 8 + hl) * 4096 + seqg) * 64;
#pragma unroll
        for (int u = 0; u < 8; u++)
            *(short8*)(drow + u * 8) = *(const short8*)&sT[seqlocal][hl_loc * 64 + u * 8];
    } else {
        // V: pack 4 consecutive seq into b64 LDS writes, then coalesced b128
#pragma unroll
        for (int j = 0; j < 4; j++) {
            const int jcl = j0 + j * 16 + l15;             // 0..127
            const float bs = bias[nbase + jcl];
#pragma unroll
            for (int i = 0; i < 4; i++) {
                uint2 w;
                w.x = pack2(acc[i][j][0] + bs, acc[i][j][1] + bs);
                w.y = pack2(acc[i][j][2] + bs, acc[i][j][3] + bs);
                *(uint2*)&sT[jcl][(wv >> 1) * 64 + i * 16 + quad * 4] = w;
            }
        }
        __syncthreads();

        const int jcl = tid >> 1, half = tid & 1;
        const int hl = (bis * 128 + jcl) >> 6;
        const int d  = jcl & 63;
        const int bb = (blockIdx.x * 128) >> 12;
        const int seq0 = ((blockIdx.x * 128) & 4095) + half * 64;
        short* dst = Vb + ((size_t)(bb * 8 + hl) * 64 + d) * 4096 + seq0;
#pragma unroll
        for (int u = 0; u < 8; u++)
            *(short8*)(dst + u * 8) = *(const short8*)&sT[jcl][half * 64 + u * 8];
    }
}

// ---------------------------------------------------------------------------
// Flash attention — byte-identical to r7's proven 76.5us kernel: dbuf, ONE
// barrier/tile, register-P via bit2<->3-swapped V LDS, o2 row-sum on the
// MFMA pipe, wave stagger, cvtpk. Latency-bound at 4 waves/SIMD.
// Split-K=2 partials (no-max streaming softmax): O = (l0*O0+l1*O1)/(l0+l1).
// ---------------------------------------------------------------------------
__global__ __launch_bounds__(512, 4) void flash_attn(
    const short* __restrict__ Q, const short* __restrict__ K,
    const short* __restrict__ V, short* __restrict__ PO0,
    short* __restrict__ PO1, float* __restrict__ lbuf, int niter)
{
    __shared__ short sK[2][128][72];     // [buf][key][d], +8 pad
    __shared__ short sV[2][64][136];     // [buf][d][key-bitswapped], +8 pad

    const int tid  = threadIdx.x;
    const int wv   = tid >> 6;            // 0..7
    const int lane = tid & 63;
    const int l31  = lane & 31;
    const int half = lane >> 5;           // 0/1
    const int bh = blockIdx.y;
    const int b = bh >> 3, h = bh & 7;
    const int qw = blockIdx.x * 256 + wv * 32;   // wave's 32 queries
    const int ks = blockIdx.z;
    const int key0 = ks * niter * 128;

    const short* Qb = Q + (size_t)bh * 4096 * 64;
    const short* Kb = K + (size_t)bh * 4096 * 64;
    const short* Vb = V + (size_t)bh * 64 * 4096;

    // Q B-frags: B[k=d][n=query l31]; step s covers d = s*16 + half*8 + j
    short8 aq[4];
#pragma unroll
    for (int s = 0; s < 4; s++)
        aq[s] = *(const short8*)(Qb + (size_t)(qw + l31) * 64 + s * 16 + half * 8);

    // ones A-frag for the row-sum MFMA (bf16 1.0 = 0x3F80)
    short8 ones;
#pragma unroll
    for (int j = 0; j < 8; j++) ones[j] = (short)0x3F80;

    f32x16 o0 = {}, o1 = {};              // O^T acc, d-tiles 0/1 (col=query)
    f32x16 o2 = {};                       // row-sum acc (any reg = lsum)

    // staging: 512 threads x (2 K-chunks + 2 V-chunks) per 128-key tile
    const int r0  = tid >> 3;             // 0..63
    const int scb = (tid & 7) * 8;        // 0..56
    const int vb  = (scb & ~12) | ((scb & 8) >> 1);  // bit2<->bit3 swap base

    short8 pk0, pk1, pv0, pv1;
    // tile 0 -> buf 0 (no barrier needed yet: LDS untouched)
    pk0 = *(const short8*)(Kb + (size_t)(key0 + r0) * 64 + scb);
    pk1 = *(const short8*)(Kb + (size_t)(key0 + 64 + r0) * 64 + scb);
    pv0 = *(const short8*)(Vb + (size_t)r0 * 4096 + key0 + scb);
    pv1 = *(const short8*)(Vb + (size_t)r0 * 4096 + key0 + 64 + scb);
    *(short8*)&sK[0][r0][scb]      = pk0;
    *(short8*)&sK[0][64 + r0][scb] = pk1;
    *(uint2*)&sV[0][r0][vb]          = ((const uint2*)&pv0)[0];
    *(uint2*)&sV[0][r0][vb + 8]      = ((const uint2*)&pv0)[1];
    *(uint2*)&sV[0][r0][64 + vb]     = ((const uint2*)&pv1)[0];
    *(uint2*)&sV[0][r0][64 + vb + 8] = ((const uint2*)&pv1)[1];
    // prefetch tile 1 into regs
    {
        const int kn = key0 + 128;
        pk0 = *(const short8*)(Kb + (size_t)(kn + r0) * 64 + scb);
        pk1 = *(const short8*)(Kb + (size_t)(kn + 64 + r0) * 64 + scb);
        pv0 = *(const short8*)(Vb + (size_t)r0 * 4096 + kn + scb);
        pv1 = *(const short8*)(Vb + (size_t)r0 * 4096 + kn + 64 + scb);
    }

    for (int kt = 0; kt < niter; ++kt) {
        __syncthreads();   // buf[kt&1] writes visible; prev reads of buf[(kt+1)&1] done

        if (kt + 1 < niter) {          // write tile kt+1 to the other buffer
            short (*sKn)[72]  = sK[(kt + 1) & 1];
            short (*sVn)[136] = sV[(kt + 1) & 1];
            *(short8*)&sKn[r0][scb]      = pk0;
            *(short8*)&sKn[64 + r0][scb] = pk1;
            *(uint2*)&sVn[r0][vb]          = ((const uint2*)&pv0)[0];
            *(uint2*)&sVn[r0][vb + 8]      = ((const uint2*)&pv0)[1];
            *(uint2*)&sVn[r0][64 + vb]     = ((const uint2*)&pv1)[0];
            *(uint2*)&sVn[r0][64 + vb + 8] = ((const uint2*)&pv1)[1];
        }
        if (kt + 2 < niter) {          // issue global loads for tile kt+2
            const int kn = key0 + (kt + 2) * 128;
            pk0 = *(const short8*)(Kb + (size_t)(kn + r0) * 64 + scb);
            pk1 = *(const short8*)(Kb + (size_t)(kn + 64 + r0) * 64 + scb);
            pv0 = *(const short8*)(Vb + (size_t)r0 * 4096 + kn + scb);
            pv1 = *(const short8*)(Vb + (size_t)r0 * 4096 + kn + 64 + scb);
        }

        const short (*sKc)[72]  = sK[kt & 1];
        const short (*sVc)[136] = sV[kt & 1];

        // 4 c-subtiles of 32 keys, WAVE-ROTATED order: c = (i + wv) & 3.
        // S^T C/D: col=query l31, reg r holds key c*32 + (r&3)+8*(r>>2)+4*half
#pragma unroll
        for (int i = 0; i < 4; i++) {
            const int c = (i + wv) & 3;
            f32x16 ST = {};
            __builtin_amdgcn_s_setprio(1);
#pragma unroll
            for (int s = 0; s < 4; s++) {
                const short8 bk = *(const short8*)&sKc[c * 32 + l31][s * 16 + half * 8];
                ST = MFMA32(bk, aq[s], ST);
            }
            __builtin_amdgcn_s_setprio(0);
            float e[16];
#pragma unroll
            for (int r = 0; r < 16; r++) e[r] = EXP2(ST[r]);
            uint4 w0 = { cvtpk(e[0], e[1]),   cvtpk(e[2], e[3]),
                         cvtpk(e[4], e[5]),   cvtpk(e[6], e[7]) };
            uint4 w1 = { cvtpk(e[8], e[9]),   cvtpk(e[10], e[11]),
                         cvtpk(e[12], e[13]), cvtpk(e[14], e[15]) };
            const short8 bp0 = *(const short8*)&w0;   // PV B-frag, step t=2c
            const short8 bp1 = *(const short8*)&w1;   // step t=2c+1

            // O^T += V^T x P^T ; o2 += 1 x P^T (row sums on the MFMA pipe)
            __builtin_amdgcn_s_setprio(1);
            const short8 bv00 = *(const short8*)&sVc[l31][(2 * c) * 16 + half * 8];
            const short8 bv01 = *(const short8*)&sVc[32 + l31][(2 * c) * 16 + half * 8];
            o0 = MFMA32(bv00, bp0, o0);
            o1 = MFMA32(bv01, bp0, o1);
            o2 = MFMA32(ones, bp0, o2);
            const short8 bv10 = *(const short8*)&sVc[l31][(2 * c + 1) * 16 + half * 8];
            const short8 bv11 = *(const short8*)&sVc[32 + l31][(2 * c + 1) * 16 + half * 8];
            o0 = MFMA32(bv10, bp1, o0);
            o1 = MFMA32(bv11, bp1, o1);
            o2 = MFMA32(ones, bp1, o2);
            __builtin_amdgcn_s_setprio(0);
        }
    }

    // o2[0] = full row sum for query l31 (all keys, both halves, all tiles)
    const float lsum = o2[0];
    const float inv = 1.f / fmaxf(lsum, 1e-30f);

    short* PO = (ks == 0) ? PO0 : PO1;
    // O^T: reg-quad q = 4 consecutive d at 8q + 4*half (+32 for o1), query l31
#pragma unroll
    for (int q = 0; q < 4; q++) {
        uint2 w0, w1;
        w0.x = pack2(o0[4 * q + 0] * inv, o0[4 * q + 1] * inv);
        w0.y = pack2(o0[4 * q + 2] * inv, o0[4 * q + 3] * inv);
        w1.x = pack2(o1[4 * q + 0] * inv, o1[4 * q + 1] * inv);
        w1.y = pack2(o1[4 * q + 2] * inv, o1[4 * q + 3] * inv);
        const size_t rowoff = ((size_t)b * 4096 + qw + l31) * 512;
        const int col = h * 64 + q * 8 + half * 4;
        *(uint2*)(PO + rowoff + col) = w0;
        *(uint2*)(PO + rowoff + col + 32) = w1;
    }
    if (half == 0)
        lbuf[((size_t)ks * 16 + bh) * 4096 + qw + l31] = lsum;
}

// ---------------------------------------------------------------------------
// Projection r25 — combine fused, data path FIXED vs r24: W is bf16 (pwb
// via cvt3, short8 loads), fully-unrolled 16-step K-loop with ONE-STEP
// register prefetch of a0/a1/b, and L-weights for head h+1 computed while
// step st+1's loads are in flight. comb8 (8 VALU + 4 cvtpk) rides the
// otherwise-idle VALU pipe. Swapped-operand MFMA16(b,a) -> contiguous
// float4 stores. Grid (128,4) = 512 blocks = 2/CU.
// ---------------------------------------------------------------------------
__global__ __launch_bounds__(256) void proj_fused(
    const short* __restrict__ PO0, const short* __restrict__ PO1,
    const float* __restrict__ L, const short* __restrict__ W,
    const float* __restrict__ bias, float* __restrict__ dst)
{
    const int tid  = threadIdx.x;
    const int wv   = tid >> 6;
    const int lane = tid & 63;
    const int l15  = lane & 15;
    const int quad = lane >> 4;
    const int m0 = blockIdx.x * 64;                 // 0..8191 (128 tiles)
    const int n0 = blockIdx.y * 128 + wv * 32;      // 0..511
    const int bb = m0 >> 12;                        // batch (tile-uniform)

    const f32x4 zero = {0.f, 0.f, 0.f, 0.f};
    f32x4 acc[4][2];
#pragma unroll
    for (int i = 0; i < 4; i++)
#pragma unroll
        for (int j = 0; j < 2; j++) acc[i][j] = zero;

    const short* A0row = PO0 + (size_t)(m0 + l15) * 512 + quad * 8;
    const short* A1row = PO1 + (size_t)(m0 + l15) * 512 + quad * 8;
    const short* Brow  = W + (size_t)(n0 + l15) * 512 + quad * 8;

    // per-row l-offsets (head-invariant part)
    size_t loff[4];
#pragma unroll
    for (int i = 0; i < 4; i++)
        loff[i] = (size_t)(bb * 8) * 4096 + ((m0 + i * 16 + l15) & 4095);

    // weights for head 0
    float w0v[4], w1v[4];
#pragma unroll
    for (int i = 0; i < 4; i++) {
        const float l0 = L[loff[i]];
        const float l1 = L[65536 + loff[i]];
        const float inv = 1.f / (l0 + l1);
        w0v[i] = l0 * inv; w1v[i] = l1 * inv;
    }

    // preload step 0 raw fragments (k0 = 0)
    short8 ca0[4], ca1[4], cb[2];
#pragma unroll
    for (int i = 0; i < 4; i++) {
        ca0[i] = *(const short8*)(A0row + (size_t)i * 16 * 512);
        ca1[i] = *(const short8*)(A1row + (size_t)i * 16 * 512);
    }
#pragma unroll
    for (int j = 0; j < 2; j++) cb[j] = *(const short8*)(Brow + (size_t)j * 16 * 512);

#pragma unroll
    for (int st = 0; st < 16; ++st) {
        short8 na0[4], na1[4], nb[2];
        float nw0[4], nw1[4];
        const bool more = (st + 1 < 16);
        const bool hchange = more && (((st + 1) >> 1) != (st >> 1));
        if (more) {
            const int kn = (st + 1) * 32;
#pragma unroll
            for (int i = 0; i < 4; i++) {
                na0[i] = *(const short8*)(A0row + (size_t)i * 16 * 512 + kn);
                na1[i] = *(const short8*)(A1row + (size_t)i * 16 * 512 + kn);
            }
#pragma unroll
            for (int j = 0; j < 2; j++) nb[j] = *(const short8*)(Brow + (size_t)j * 16 * 512 + kn);
        }
        if (hchange) {
            const int hn = (st + 1) >> 1;
#pragma unroll
            for (int i = 0; i < 4; i++) {
                const float l0 = L[(size_t)hn * 4096 + loff[i]];
                const float l1 = L[65536 + (size_t)hn * 4096 + loff[i]];
                const float inv = 1.f / (l0 + l1);
                nw0[i] = l0 * inv; nw1[i] = l1 * inv;
            }
        }

        // combine current step's A-frags, MFMA (swapped operands)
        short8 a[4];
#pragma unroll
        for (int i = 0; i < 4; i++) a[i] = comb8(ca0[i], ca1[i], w0v[i], w1v[i]);
#pragma unroll
        for (int i = 0; i < 4; i++)
#pragma unroll
            for (int j = 0; j < 2; j++)
                acc[i][j] = MFMA16(cb[j], a[i], acc[i][j]);

        if (more) {
#pragma unroll
            for (int i = 0; i < 4; i++) { ca0[i] = na0[i]; ca1[i] = na1[i]; }
#pragma unroll
            for (int j = 0; j < 2; j++) cb[j] = nb[j];
            if (hchange) {
#pragma unroll
                for (int i = 0; i < 4; i++) { w0v[i] = nw0[i]; w1v[i] = nw1[i]; }
            }
        }
    }

    // acc[i][j][r] = out[m0 + i*16 + l15][n0 + j*16 + quad*4 + r]
#pragma unroll
    for (int i = 0; i < 4; i++) {
        const int m = m0 + i * 16 + l15;
#pragma unroll
        for (int j = 0; j < 2; j++) {
            const int n = n0 + j * 16 + quad * 4;
            const float4 bs = *(const float4*)(bias + n);
            float4 o;
            o.x = acc[i][j][0] + bs.x;
            o.y = acc[i][j][1] + bs.y;
            o.z = acc[i][j][2] + bs.z;
            o.w = acc[i][j][3] + bs.w;
            *(float4*)(dst + (size_t)m * 512 + n) = o;
        }
    }
}

// ---------------------------------------------------------------------------
// Memory plan — 4 dispatches, read/write sets disjoint per kernel:
//   cvt3:  reads f32 inputs; writes xb(ws[8,16M)), wb(ws[16,17.5M)),
//          pwb(ws[24.5,25M))
//   qkv:   reads xb,wb; writes Qf(ws[0,8M)), Kf(d_out[0,8M)), Vf(d_out[8,16M))
//   flash: reads Qf,Kf,Vf; writes PO0(ws[8,16M), xb dead),
//          PO1(ws[16,24M), wb dead), lbuf(ws[24,24.5M))
//   proj:  reads PO0,PO1,lbuf,pwb; writes d_out f32 [0,16M) (Kf/Vf dead)
// ---------------------------------------------------------------------------
extern "C" void kernel_launch(void* const* d_in, const int* in_sizes, int n_in,
                              void* d_out, int out_size, void* d_ws, size_t ws_size,
                              hipStream_t stream)
{
    const float* x      = (const float*)d_in[0];   // [2,4096,512] f32
    const float* qkv_w  = (const float*)d_in[1];   // [1536,512]   f32
    const float* qkv_b  = (const float*)d_in[2];   // [1536]       f32
    const float* proj_w = (const float*)d_in[3];   // [512,512]    f32
    const float* proj_b = (const float*)d_in[4];   // [512]        f32

    const size_t MB = 1024 * 1024;
    short* Kf  = (short*)d_out;                        // d_out [0,8M)
    short* Vf  = (short*)d_out + 4 * MB;               // d_out [8,16M), [bh][64][seq]
    float* out = (float*)d_out;                        // proj output [0,16M)

    short* Qf   = (short*)d_ws;                        // ws [0,8M)
    short* xb   = (short*)((char*)d_ws + 8 * MB);      // ws [8,16M), dead after qkv
    short* wb   = (short*)((char*)d_ws + 16 * MB);     // ws [16,17.5M), dead after qkv
    short* PO0  = xb;                                  // ws [8,16M), post-qkv life
    short* PO1  = wb;                                  // ws [16,24M), post-qkv life
    float* lbuf = (float*)((char*)d_ws + 24 * MB);     // ws [24,24.5M)
    short* pwb  = (short*)((char*)d_ws + 24 * MB + 512 * 1024);  // ws [24.5,25M)

    cvt3<<<2560, 256, 0, stream>>>(x, xb, 524288, qkv_w, wb, 98304, proj_w, pwb, 32768);
    qkv_gemm<<<dim3(64, 12), 256, 0, stream>>>(xb, wb, qkv_b, Qf, Kf, Vf);
    flash_attn<<<dim3(16, 16, 2), 512, 0, stream>>>(Qf, Kf, Vf, PO0, PO1, lbuf, 16);
    proj_fused<<<dim3(128, 4), 256, 0, stream>>>(PO0, PO1, lbuf, pwb, proj_b, out);
}

// Round 10
// 234.773 us; speedup vs baseline: 1.2284x; 1.0444x over previous
//
#include <hip/hip_runtime.h>
#include <hip/hip_bf16.h>
#include <stdint.h>
#include <stddef.h>

typedef __attribute__((ext_vector_type(8))) short short8;
typedef __attribute__((ext_vector_type(4))) float f32x4;
typedef __attribute__((ext_vector_type(16))) float f32x16;

#define MFMA16(a, b, c) __builtin_amdgcn_mfma_f32_16x16x32_bf16((a), (b), (c), 0, 0, 0)
#define MFMA32(a, b, c) __builtin_amdgcn_mfma_f32_32x32x16_bf16((a), (b), (c), 0, 0, 0)

// Q pre-scale: HEAD_DIM^-0.5 * log2(e); flash uses raw v_exp_f32 (exp2)
#define QSCALE 0.1803368801111204f

#if __has_builtin(__builtin_amdgcn_exp2f)
#define EXP2(x) __builtin_amdgcn_exp2f(x)
#else
#define EXP2(x) __builtin_exp2f(x)
#endif

__device__ __forceinline__ float b2f(short x) {
    unsigned u = ((unsigned)(unsigned short)x) << 16;
    float f; __builtin_memcpy(&f, &u, 4); return f;
}
// round-nearest-even f32->bf16 (scalar)
__device__ __forceinline__ short f2b(float f) {
    unsigned u; __builtin_memcpy(&u, &f, 4);
    u = (u + 0x7FFFu + ((u >> 16) & 1u)) >> 16;
    return (short)u;
}
// two f32 -> packed bf16x2 in 3 VALU (2 adds + v_perm), round-half-up.
__device__ __forceinline__ unsigned pack2(float a, float b) {
    unsigned ua, ub; __builtin_memcpy(&ua, &a, 4); __builtin_memcpy(&ub, &b, 4);
    return __builtin_amdgcn_perm(ub + 0x8000u, ua + 0x8000u, 0x07060302u);
}
// two f32 -> packed bf16x2 in ONE VALU (RNE). low=a, high=b.
__device__ __forceinline__ unsigned cvtpk(float a, float b) {
    unsigned r;
    asm("v_cvt_pk_bf16_f32 %0, %1, %2" : "=v"(r) : "v"(a), "v"(b));
    return r;
}
// 8 contiguous f32 -> bf16x8 (RNE)
__device__ __forceinline__ short8 load8f(const float* p) {
    const float4 f0 = *(const float4*)p;
    const float4 f1 = *(const float4*)(p + 4);
    short8 r;
    r[0]=f2b(f0.x); r[1]=f2b(f0.y); r[2]=f2b(f0.z); r[3]=f2b(f0.w);
    r[4]=f2b(f1.x); r[5]=f2b(f1.y); r[6]=f2b(f1.z); r[7]=f2b(f1.w);
    return r;
}

// ---------------------------------------------------------------------------
// Fused f32->bf16 converter for up to 3 arrays. nX = elems/8.
// ---------------------------------------------------------------------------
__global__ __launch_bounds__(256) void cvt3(
    const float* __restrict__ s0, short* __restrict__ d0, int n0,
    const float* __restrict__ s1, short* __restrict__ d1, int n1,
    const float* __restrict__ s2, short* __restrict__ d2, int n2)
{
    int i = blockIdx.x * 256 + threadIdx.x;
    if (i < n0) { *(short8*)(d0 + (size_t)i * 8) = load8f(s0 + (size_t)i * 8); return; }
    i -= n0;
    if (i < n1) { *(short8*)(d1 + (size_t)i * 8) = load8f(s1 + (size_t)i * 8); return; }
    i -= n1;
    if (i < n2) { *(short8*)(d2 + (size_t)i * 8) = load8f(s2 + (size_t)i * 8); }
}

// ---------------------------------------------------------------------------
// Fused QKV GEMM (bf16 in/out) — the r5-bundle version VERBATIM (best
// measured non-flash stack). Rolled K-loop, LDS-staged epilogues for
// Q/K (row streams) and V (transpose). Grid (64,12): sec = y>>2.
// ---------------------------------------------------------------------------
__global__ __launch_bounds__(256) void qkv_gemm(
    const short* __restrict__ X, const short* __restrict__ W,
    const float* __restrict__ bias,
    short* __restrict__ Qb, short* __restrict__ Kb, short* __restrict__ Vb)
{
    __shared__ short sT[128][132];

    const int tid  = threadIdx.x;
    const int wv   = tid >> 6;
    const int lane = tid & 63;
    const int l15  = lane & 15;
    const int quad = lane >> 4;
    const int m0   = blockIdx.x * 128 + (wv >> 1) * 64;
    const int sec  = blockIdx.y >> 2;
    const int bis  = blockIdx.y & 3;
    const int nbase = sec * 512 + bis * 128;
    const int j0   = (wv & 1) * 64;

    const f32x4 zero = {0.f, 0.f, 0.f, 0.f};
    f32x4 acc[4][4];
#pragma unroll
    for (int i = 0; i < 4; i++)
#pragma unroll
        for (int j = 0; j < 4; j++) acc[i][j] = zero;

    for (int k0 = 0; k0 < 512; k0 += 32) {
        short8 a[4], b[4];
#pragma unroll
        for (int i = 0; i < 4; i++)
            a[i] = *(const short8*)(X + (size_t)(m0 + i * 16 + l15) * 512 + k0 + quad * 8);
#pragma unroll
        for (int j = 0; j < 4; j++)
            b[j] = *(const short8*)(W + (size_t)(nbase + j0 + j * 16 + l15) * 512 + k0 + quad * 8);
#pragma unroll
        for (int i = 0; i < 4; i++)
#pragma unroll
            for (int j = 0; j < 4; j++)
                acc[i][j] = MFMA16(a[i], b[j], acc[i][j]);
    }

    if (sec < 2) {
        const float scale = (sec == 0) ? QSCALE : 1.0f;
        short* dst = (sec == 0) ? Qb : Kb;
        // stage into sT[seqlocal][jcl]: 128 seq x 128 section-cols
#pragma unroll
        for (int j = 0; j < 4; j++) {
            const int jcl = j0 + j * 16 + l15;              // 0..127 block-local col
            const float bs = bias[sec * 512 + bis * 128 + jcl];
#pragma unroll
            for (int i = 0; i < 4; i++) {
                const int s0 = (wv >> 1) * 64 + i * 16 + quad * 4;  // seqlocal base
#pragma unroll
                for (int r = 0; r < 4; r++)
                    sT[s0 + r][jcl] = f2b((acc[i][j][r] + bs) * scale);
            }
        }
        __syncthreads();

        // write out: 256 rows (2 hl x 128 seq); thread owns one 128-B row
        const int seqlocal = tid & 127;
        const int hl_loc   = tid >> 7;                      // 0/1
        const int hl  = bis * 2 + hl_loc;
        const int m   = blockIdx.x * 128 + seqlocal;
        const int bb  = m >> 12, seqg = m & 4095;
        short* drow = dst + ((size_t)(bb * 8 + hl) * 4096 + seqg) * 64;
#pragma unroll
        for (int u = 0; u < 8; u++)
            *(short8*)(drow + u * 8) = *(const short8*)&sT[seqlocal][hl_loc * 64 + u * 8];
    } else {
        // V: pack 4 consecutive seq into b64 LDS writes, then coalesced b128
#pragma unroll
        for (int j = 0; j < 4; j++) {
            const int jcl = j0 + j * 16 + l15;             // 0..127
            const float bs = bias[nbase + jcl];
#pragma unroll
            for (int i = 0; i < 4; i++) {
                uint2 w;
                w.x = pack2(acc[i][j][0] + bs, acc[i][j][1] + bs);
                w.y = pack2(acc[i][j][2] + bs, acc[i][j][3] + bs);
                *(uint2*)&sT[jcl][(wv >> 1) * 64 + i * 16 + quad * 4] = w;
            }
        }
        __syncthreads();

        const int jcl = tid >> 1, half = tid & 1;
        const int hl = (bis * 128 + jcl) >> 6;
        const int d  = jcl & 63;
        const int bb = (blockIdx.x * 128) >> 12;
        const int seq0 = ((blockIdx.x * 128) & 4095) + half * 64;
        short* dst = Vb + ((size_t)(bb * 8 + hl) * 64 + d) * 4096 + seq0;
#pragma unroll
        for (int u = 0; u < 8; u++)
            *(short8*)(dst + u * 8) = *(const short8*)&sT[jcl][half * 64 + u * 8];
    }
}

// ---------------------------------------------------------------------------
// Flash attention — byte-identical to the proven 76.5us kernel (r7): dbuf,
// ONE barrier/tile, register-P via bit2<->3-swapped V LDS, o2 row-sum on
// the MFMA pipe, wave stagger, cvtpk. Latency-bound at 4 waves/SIMD.
// Split-K=2 partials (no-max streaming softmax): O = (l0*O0+l1*O1)/(l0+l1).
// ---------------------------------------------------------------------------
__global__ __launch_bounds__(512, 4) void flash_attn(
    const short* __restrict__ Q, const short* __restrict__ K,
    const short* __restrict__ V, short* __restrict__ PO0,
    short* __restrict__ PO1, float* __restrict__ lbuf, int niter)
{
    __shared__ short sK[2][128][72];     // [buf][key][d], +8 pad
    __shared__ short sV[2][64][136];     // [buf][d][key-bitswapped], +8 pad

    const int tid  = threadIdx.x;
    const int wv   = tid >> 6;            // 0..7
    const int lane = tid & 63;
    const int l31  = lane & 31;
    const int half = lane >> 5;           // 0/1
    const int bh = blockIdx.y;
    const int b = bh >> 3, h = bh & 7;
    const int qw = blockIdx.x * 256 + wv * 32;   // wave's 32 queries
    const int ks = blockIdx.z;
    const int key0 = ks * niter * 128;

    const short* Qb = Q + (size_t)bh * 4096 * 64;
    const short* Kb = K + (size_t)bh * 4096 * 64;
    const short* Vb = V + (size_t)bh * 64 * 4096;

    // Q B-frags: B[k=d][n=query l31]; step s covers d = s*16 + half*8 + j
    short8 aq[4];
#pragma unroll
    for (int s = 0; s < 4; s++)
        aq[s] = *(const short8*)(Qb + (size_t)(qw + l31) * 64 + s * 16 + half * 8);

    // ones A-frag for the row-sum MFMA (bf16 1.0 = 0x3F80)
    short8 ones;
#pragma unroll
    for (int j = 0; j < 8; j++) ones[j] = (short)0x3F80;

    f32x16 o0 = {}, o1 = {};              // O^T acc, d-tiles 0/1 (col=query)
    f32x16 o2 = {};                       // row-sum acc (any reg = lsum)

    // staging: 512 threads x (2 K-chunks + 2 V-chunks) per 128-key tile
    const int r0  = tid >> 3;             // 0..63
    const int scb = (tid & 7) * 8;        // 0..56
    const int vb  = (scb & ~12) | ((scb & 8) >> 1);  // bit2<->bit3 swap base

    short8 pk0, pk1, pv0, pv1;
    // tile 0 -> buf 0 (no barrier needed yet: LDS untouched)
    pk0 = *(const short8*)(Kb + (size_t)(key0 + r0) * 64 + scb);
    pk1 = *(const short8*)(Kb + (size_t)(key0 + 64 + r0) * 64 + scb);
    pv0 = *(const short8*)(Vb + (size_t)r0 * 4096 + key0 + scb);
    pv1 = *(const short8*)(Vb + (size_t)r0 * 4096 + key0 + 64 + scb);
    *(short8*)&sK[0][r0][scb]      = pk0;
    *(short8*)&sK[0][64 + r0][scb] = pk1;
    *(uint2*)&sV[0][r0][vb]          = ((const uint2*)&pv0)[0];
    *(uint2*)&sV[0][r0][vb + 8]      = ((const uint2*)&pv0)[1];
    *(uint2*)&sV[0][r0][64 + vb]     = ((const uint2*)&pv1)[0];
    *(uint2*)&sV[0][r0][64 + vb + 8] = ((const uint2*)&pv1)[1];
    // prefetch tile 1 into regs
    {
        const int kn = key0 + 128;
        pk0 = *(const short8*)(Kb + (size_t)(kn + r0) * 64 + scb);
        pk1 = *(const short8*)(Kb + (size_t)(kn + 64 + r0) * 64 + scb);
        pv0 = *(const short8*)(Vb + (size_t)r0 * 4096 + kn + scb);
        pv1 = *(const short8*)(Vb + (size_t)r0 * 4096 + kn + 64 + scb);
    }

    for (int kt = 0; kt < niter; ++kt) {
        __syncthreads();   // buf[kt&1] writes visible; prev reads of buf[(kt+1)&1] done

        if (kt + 1 < niter) {          // write tile kt+1 to the other buffer
            short (*sKn)[72]  = sK[(kt + 1) & 1];
            short (*sVn)[136] = sV[(kt + 1) & 1];
            *(short8*)&sKn[r0][scb]      = pk0;
            *(short8*)&sKn[64 + r0][scb] = pk1;
            *(uint2*)&sVn[r0][vb]          = ((const uint2*)&pv0)[0];
            *(uint2*)&sVn[r0][vb + 8]      = ((const uint2*)&pv0)[1];
            *(uint2*)&sVn[r0][64 + vb]     = ((const uint2*)&pv1)[0];
            *(uint2*)&sVn[r0][64 + vb + 8] = ((const uint2*)&pv1)[1];
        }
        if (kt + 2 < niter) {          // issue global loads for tile kt+2
            const int kn = key0 + (kt + 2) * 128;
            pk0 = *(const short8*)(Kb + (size_t)(kn + r0) * 64 + scb);
            pk1 = *(const short8*)(Kb + (size_t)(kn + 64 + r0) * 64 + scb);
            pv0 = *(const short8*)(Vb + (size_t)r0 * 4096 + kn + scb);
            pv1 = *(const short8*)(Vb + (size_t)r0 * 4096 + kn + 64 + scb);
        }

        const short (*sKc)[72]  = sK[kt & 1];
        const short (*sVc)[136] = sV[kt & 1];

        // 4 c-subtiles of 32 keys, WAVE-ROTATED order: c = (i + wv) & 3.
        // S^T C/D: col=query l31, reg r holds key c*32 + (r&3)+8*(r>>2)+4*half
#pragma unroll
        for (int i = 0; i < 4; i++) {
            const int c = (i + wv) & 3;
            f32x16 ST = {};
            __builtin_amdgcn_s_setprio(1);
#pragma unroll
            for (int s = 0; s < 4; s++) {
                const short8 bk = *(const short8*)&sKc[c * 32 + l31][s * 16 + half * 8];
                ST = MFMA32(bk, aq[s], ST);
            }
            __builtin_amdgcn_s_setprio(0);
            float e[16];
#pragma unroll
            for (int r = 0; r < 16; r++) e[r] = EXP2(ST[r]);
            uint4 w0 = { cvtpk(e[0], e[1]),   cvtpk(e[2], e[3]),
                         cvtpk(e[4], e[5]),   cvtpk(e[6], e[7]) };
            uint4 w1 = { cvtpk(e[8], e[9]),   cvtpk(e[10], e[11]),
                         cvtpk(e[12], e[13]), cvtpk(e[14], e[15]) };
            const short8 bp0 = *(const short8*)&w0;   // PV B-frag, step t=2c
            const short8 bp1 = *(const short8*)&w1;   // step t=2c+1

            // O^T += V^T x P^T ; o2 += 1 x P^T (row sums on the MFMA pipe)
            __builtin_amdgcn_s_setprio(1);
            const short8 bv00 = *(const short8*)&sVc[l31][(2 * c) * 16 + half * 8];
            const short8 bv01 = *(const short8*)&sVc[32 + l31][(2 * c) * 16 + half * 8];
            o0 = MFMA32(bv00, bp0, o0);
            o1 = MFMA32(bv01, bp0, o1);
            o2 = MFMA32(ones, bp0, o2);
            const short8 bv10 = *(const short8*)&sVc[l31][(2 * c + 1) * 16 + half * 8];
            const short8 bv11 = *(const short8*)&sVc[32 + l31][(2 * c + 1) * 16 + half * 8];
            o0 = MFMA32(bv10, bp1, o0);
            o1 = MFMA32(bv11, bp1, o1);
            o2 = MFMA32(ones, bp1, o2);
            __builtin_amdgcn_s_setprio(0);
        }
    }

    // o2[0] = full row sum for query l31 (all keys, both halves, all tiles)
    const float lsum = o2[0];
    const float inv = 1.f / fmaxf(lsum, 1e-30f);

    short* PO = (ks == 0) ? PO0 : PO1;
    // O^T: reg-quad q = 4 consecutive d at 8q + 4*half (+32 for o1), query l31
#pragma unroll
    for (int q = 0; q < 4; q++) {
        uint2 w0, w1;
        w0.x = pack2(o0[4 * q + 0] * inv, o0[4 * q + 1] * inv);
        w0.y = pack2(o0[4 * q + 2] * inv, o0[4 * q + 3] * inv);
        w1.x = pack2(o1[4 * q + 0] * inv, o1[4 * q + 1] * inv);
        w1.y = pack2(o1[4 * q + 2] * inv, o1[4 * q + 3] * inv);
        const size_t rowoff = ((size_t)b * 4096 + qw + l31) * 512;
        const int col = h * 64 + q * 8 + half * 4;
        *(uint2*)(PO + rowoff + col) = w0;
        *(uint2*)(PO + rowoff + col + 32) = w1;
    }
    if (half == 0)
        lbuf[((size_t)ks * 16 + bh) * 4096 + qw + l31] = lsum;
}

// ---------------------------------------------------------------------------
// Combine the 2 key-split partials: attn(ws) = (l0*O0 + l1*O1)/(l0+l1).
// ---------------------------------------------------------------------------
__global__ __launch_bounds__(256) void combine(
    const short* __restrict__ PO0, const short* __restrict__ PO1,
    short* __restrict__ attn, const float* __restrict__ L)
{
    const int i = blockIdx.x * 256 + threadIdx.x;   // 0..524287
    const size_t flat = (size_t)i * 8;
    const int col = (int)(flat & 511);
    const int q   = (int)((flat >> 9) & 4095);
    const int b   = (int)(flat >> 21);
    const int bh  = b * 8 + (col >> 6);
    const float l0 = L[(size_t)bh * 4096 + q];
    const float l1 = L[(size_t)65536 + (size_t)bh * 4096 + q];
    const float inv = 1.f / (l0 + l1);
    const float w0 = l0 * inv, w1 = l1 * inv;
    const short8 a = *(const short8*)(PO0 + flat);
    const short8 c = *(const short8*)(PO1 + flat);
    short8 r;
#pragma unroll
    for (int k = 0; k < 8; k += 2) {
        const unsigned p = pack2(w0 * b2f(a[k]) + w1 * b2f(c[k]),
                                 w0 * b2f(a[k + 1]) + w1 * b2f(c[k + 1]));
        r[k]     = (short)(p & 0xFFFF);
        r[k + 1] = (short)(p >> 16);
    }
    *(short8*)(attn + flat) = r;
}

// ---------------------------------------------------------------------------
// Projection — r5-bundle version verbatim: grid (64,4) = 256 blocks,
// rolled K-loop, direct f32 stores.
// ---------------------------------------------------------------------------
__global__ __launch_bounds__(256) void proj_gemm(
    const short* __restrict__ A, const short* __restrict__ W,
    const float* __restrict__ bias, float* __restrict__ dst)
{
    const int tid  = threadIdx.x;
    const int wv   = tid >> 6;
    const int lane = tid & 63;
    const int l15  = lane & 15;
    const int quad = lane >> 4;
    const int m0 = blockIdx.x * 128 + (wv >> 1) * 64;   // 0..8191
    const int n0 = blockIdx.y * 128 + (wv & 1) * 64;

    const f32x4 zero = {0.f, 0.f, 0.f, 0.f};
    f32x4 acc[4][4];
#pragma unroll
    for (int i = 0; i < 4; i++)
#pragma unroll
        for (int j = 0; j < 4; j++) acc[i][j] = zero;

    for (int k0 = 0; k0 < 512; k0 += 32) {
        short8 a[4], b[4];
#pragma unroll
        for (int i = 0; i < 4; i++)
            a[i] = *(const short8*)(A + (size_t)(m0 + i * 16 + l15) * 512 + k0 + quad * 8);
#pragma unroll
        for (int j = 0; j < 4; j++)
            b[j] = *(const short8*)(W + (size_t)(n0 + j * 16 + l15) * 512 + k0 + quad * 8);
#pragma unroll
        for (int i = 0; i < 4; i++)
#pragma unroll
            for (int j = 0; j < 4; j++)
                acc[i][j] = MFMA16(a[i], b[j], acc[i][j]);
    }

#pragma unroll
    for (int j = 0; j < 4; j++) {
        const int n = n0 + j * 16 + l15;
        const float bs = bias[n];
#pragma unroll
        for (int i = 0; i < 4; i++) {
#pragma unroll
            for (int r = 0; r < 4; r++) {
                const int m = m0 + i * 16 + quad * 4 + r;
                dst[(size_t)m * 512 + n] = acc[i][j][r] + bs;
            }
        }
    }
}

// ---------------------------------------------------------------------------
// Memory plan (r5-bundle, proven): 5 dispatches.
//   d_out [0,8M):    xb -> PO0 (flash split 0) -> proj output [0,8M)
//   d_out [8M,9.5M): wb (dead after qkv)
//   d_out [8M,16M):  PO1 (flash split 1) -> proj output [8M,16M)
//   ws [0,8M):  Qf -> attn (combine output; Qf dead after flash)
//   ws [8M,16M) Kf | [16M,24M) Vf | [24M,24.5M) lbuf | [24.5M,25M) pwb
// ---------------------------------------------------------------------------
extern "C" void kernel_launch(void* const* d_in, const int* in_sizes, int n_in,
                              void* d_out, int out_size, void* d_ws, size_t ws_size,
                              hipStream_t stream)
{
    const float* x      = (const float*)d_in[0];   // [2,4096,512] f32
    const float* qkv_w  = (const float*)d_in[1];   // [1536,512]   f32
    const float* qkv_b  = (const float*)d_in[2];   // [1536]       f32
    const float* proj_w = (const float*)d_in[3];   // [512,512]    f32
    const float* proj_b = (const float*)d_in[4];   // [512]        f32

    const size_t MB = 1024 * 1024;
    short* xb   = (short*)d_out;
    short* wb   = (short*)d_out + 4 * MB;
    short* PO0  = (short*)d_out;                   // [0,8M) after xb dies
    short* PO1  = (short*)d_out + 4 * MB;          // [8M,16M) after wb dies
    float* out  = (float*)d_out;

    short* Qf = (short*)d_ws;
    short* Kf = Qf + (size_t)16 * 4096 * 64;
    short* Vf = Kf + (size_t)16 * 4096 * 64;       // [bh][64][4096]
    short* attn = Qf;                              // ws [0,8M), post-flash life
    float* lbuf = (float*)((char*)d_ws + 24 * MB);
    short* pwb  = (short*)((char*)d_ws + 24 * MB + 512 * 1024);

    cvt3<<<2560, 256, 0, stream>>>(x, xb, 524288, qkv_w, wb, 98304, proj_w, pwb, 32768);
    qkv_gemm<<<dim3(64, 12), 256, 0, stream>>>(xb, wb, qkv_b, Qf, Kf, Vf);
    flash_attn<<<dim3(16, 16, 2), 512, 0, stream>>>(Qf, Kf, Vf, PO0, PO1, lbuf, 16);
    combine<<<2048, 256, 0, stream>>>(PO0, PO1, attn, lbuf);
    proj_gemm<<<dim3(64, 4), 256, 0, stream>>>(attn, pwb, proj_b, out);
}